// Round 11
// baseline (77.206 us; speedup 1.0000x reference)
//
#include <hip/hip_runtime.h>
#include <hip/hip_bf16.h>

#define BB 256
#define NLAT 128
#define HH 64
#define CC 64
#define GG 5000
#define NG 10
#define NBLK (GG / NG)      // 500 decoder blocks -> all resident in one generation
#define GSTRIDE (GG * CC)   // 320000 floats between batch rows
#define BN_EPS 1e-5f

typedef __bf16 bf16x8 __attribute__((ext_vector_type(8)));
typedef float f32x4 __attribute__((ext_vector_type(4)));

// Kernel 1: h = BN(ReLU(latent @ W1 + b1)) -> bf16 [256][64]
__global__ void hprep_kernel(const float* __restrict__ latent,
                             const float* __restrict__ W1,
                             const float* __restrict__ b1,
                             const float* __restrict__ gamma,
                             const float* __restrict__ beta,
                             const float* __restrict__ mean,
                             const float* __restrict__ var,
                             unsigned short* __restrict__ hout) {
    const int b = blockIdx.x;   // 0..255
    const int c = threadIdx.x;  // 0..63
    float acc = b1[c];
    const float* lrow = latent + b * NLAT;
#pragma unroll 8
    for (int k = 0; k < NLAT; ++k)
        acc = fmaf(lrow[k], W1[k * HH + c], acc);
    acc = fmaxf(acc, 0.f);  // ReLU first
    float s = gamma[c] * rsqrtf(var[c] + BN_EPS);
    acc = (acc - mean[c]) * s + beta[c];
    __bf16 hv = (__bf16)acc;
    hout[b * HH + c] = *reinterpret_cast<unsigned short*>(&hv);
}

// Barrier that only drains LDS ops; global loads/stores stay in flight.
__device__ __forceinline__ void barrier_lds_only() {
    asm volatile("s_waitcnt lgkmcnt(0)" ::: "memory");
    __builtin_amdgcn_s_barrier();
    asm volatile("" ::: "memory");
}

// Kernel 2: out[b,g,c] = sum_h h[b,h] * W[gene,h,c] + bias[gene,c]
// R10 structure (76.0 us best) with ONE change: NG=10 -> 500 blocks.
// 2 blocks/CU x 256 CUs = 512 resident slots >= 500 blocks: the whole grid
// is co-resident from t=0 (single generation, no refill stagger) and the
// number of exposed per-block prologues (16 KB read + lgkm drain, no
// stores in flight) halves. LDS = 80 KB (2 blocks/CU) unchanged.
__global__ __launch_bounds__(512, 4) void decoder_kernel(
    const unsigned short* __restrict__ hbuf,  // bf16 [256][64]
    const int* __restrict__ genes,            // [5000]
    const float* __restrict__ wt,             // [30000][64][64] f32
    const float* __restrict__ bt,             // [30000][64] f32
    float* __restrict__ out)                  // [256][5000][64] f32
{
    __shared__ __align__(16) unsigned short ldsW[2][4096];  // 2 x 8 KB bf16 Wt
    __shared__ __align__(16) float ldsO[BB * CC];           // 64 KB (8 KB/wave)

    const int tid = threadIdx.x;
    const int l   = tid & 63;
    const int w   = tid >> 6;   // wave 0..7
    const int l16 = l & 15;
    const int lg  = l >> 4;     // 0..3

    // Bijective chunked XCD swizzle (m204): 500 = 8*62 + 4.
    // xcd 0..3 own 63 consecutive v's, xcd 4..7 own 62.
    const int xcd = blockIdx.x & 7;
    const int k   = blockIdx.x >> 3;
    const int v   = (xcd < 4 ? xcd * 63 : 252 + (xcd - 4) * 62) + k;
    const int g0  = v * NG;

    // A fragments (persist): rows w*32 + m*16 + l16, k-contiguous 8 bf16
    bf16x8 afrag[2][2];
#pragma unroll
    for (int m = 0; m < 2; ++m)
#pragma unroll
        for (int ks = 0; ks < 2; ++ks) {
            int row = w * 32 + m * 16 + l16;
            afrag[m][ks] = *reinterpret_cast<const bf16x8*>(
                hbuf + row * HH + ks * 32 + lg * 8);
        }

    // W staging geometry: thread stages column sc of h-block shb.
    const int sc  = l;   // 0..63
    const int shb = w;   // 0..7
    const int swz16 = sc * 8 + (shb ^ (sc & 7));

    float pkv[8];

    // --- prologue: stage gene g0 into ldsW[0] (regular cached loads)
    {
        const float* Wg = wt + (size_t)genes[g0] * (HH * CC);
#pragma unroll
        for (int j = 0; j < 8; ++j)
            pkv[j] = Wg[(shb * 8 + j) * CC + sc];
        bf16x8 pk;
#pragma unroll
        for (int j = 0; j < 8; ++j) pk[j] = (__bf16)pkv[j];
        *reinterpret_cast<bf16x8*>(
            reinterpret_cast<char*>(ldsW[0]) + swz16 * 16) = pk;
    }
    barrier_lds_only();

    // wave-local ldsO region: 32 rows x 64 floats = 8 KB
    float* ldsOw = ldsO + w * (32 * CC);

    int p = 0;
#pragma unroll 2
    for (int i = 0; i < NG; ++i) {
        const int g = g0 + i;

        // 1. issue next gene's gather loads early (hide under MFMA + flush)
        if (i + 1 < NG) {
            const float* Wn = wt + (size_t)genes[g + 1] * (HH * CC);
#pragma unroll
            for (int j = 0; j < 8; ++j)
                pkv[j] = Wn[(shb * 8 + j) * CC + sc];
        }

        // 2. MFMA (operand-swapped): E[n][m] lane = (c = n*16+lg*4+r, b=l16)
        const float* bg = bt + (size_t)genes[g] * CC;
        const char* buf = reinterpret_cast<const char*>(ldsW[p]);
        f32x4 E[4][2];
#pragma unroll
        for (int n = 0; n < 4; ++n) {
            const int c = n * 16 + l16;
            bf16x8 bfr0 = *reinterpret_cast<const bf16x8*>(
                buf + (c * 8 + ((0 + lg) ^ (c & 7))) * 16);
            bf16x8 bfr1 = *reinterpret_cast<const bf16x8*>(
                buf + (c * 8 + ((4 + lg) ^ (c & 7))) * 16);
            f32x4 binit = *reinterpret_cast<const f32x4*>(bg + n * 16 + lg * 4);
#pragma unroll
            for (int m = 0; m < 2; ++m) {
                f32x4 e = binit;
                e = __builtin_amdgcn_mfma_f32_16x16x32_bf16(bfr0, afrag[m][0], e, 0, 0, 0);
                e = __builtin_amdgcn_mfma_f32_16x16x32_bf16(bfr1, afrag[m][1], e, 0, 0, 0);
                E[n][m] = e;
            }
        }

        // 3. E -> wave-local ldsO (rows r = m*16+l16; XOR-swizzled, <=2-way)
#pragma unroll
        for (int n = 0; n < 4; ++n)
#pragma unroll
            for (int m = 0; m < 2; ++m) {
                int r = m * 16 + l16;
                int unit = r * 16 + ((n * 4 + lg) ^ l16);
                *reinterpret_cast<f32x4*>(ldsOw + unit * 4) = E[n][m];
            }

        // 4. flush own rows, NON-TEMPORAL (no cross-wave barrier):
        //    each quarter-wave = one full 256B (b,g) row, conflict-free read
        {
            float* og = out + (size_t)g * CC;
#pragma unroll
            for (int it = 0; it < 8; ++it) {
                int r = it * 4 + lg;              // row within wave region
                int b = w * 32 + r;               // global batch row
                int unit = r * 16 + (l16 ^ (r & 15));
                f32x4 vv = *reinterpret_cast<const f32x4*>(ldsOw + unit * 4);
                __builtin_nontemporal_store(
                    vv, reinterpret_cast<f32x4*>(og + (size_t)b * GSTRIDE + l16 * 4));
            }
        }

        // 5. cvt + ds_write next gene's Wt into buf p^1; ONE barrier/gene
        if (i + 1 < NG) {
            bf16x8 pk;
#pragma unroll
            for (int j = 0; j < 8; ++j) pk[j] = (__bf16)pkv[j];
            *reinterpret_cast<bf16x8*>(
                reinterpret_cast<char*>(ldsW[p ^ 1]) + swz16 * 16) = pk;
            barrier_lds_only();  // all waves' reads of buf p done; p^1 visible
            p ^= 1;
        }
    }
}

extern "C" void kernel_launch(void* const* d_in, const int* in_sizes, int n_in,
                              void* d_out, int out_size, void* d_ws, size_t ws_size,
                              hipStream_t stream) {
    const float* latent = (const float*)d_in[0];
    const int*   genes  = (const int*)d_in[1];
    const float* W1     = (const float*)d_in[2];
    const float* b1     = (const float*)d_in[3];
    const float* gamma  = (const float*)d_in[4];
    const float* beta   = (const float*)d_in[5];
    const float* mean   = (const float*)d_in[6];
    const float* var    = (const float*)d_in[7];
    const float* wt     = (const float*)d_in[8];
    const float* bt     = (const float*)d_in[9];
    float* out = (float*)d_out;
    unsigned short* hbuf = (unsigned short*)d_ws;  // 32 KB bf16 h

    hprep_kernel<<<dim3(BB), dim3(HH), 0, stream>>>(latent, W1, b1, gamma, beta,
                                                    mean, var, hbuf);
    decoder_kernel<<<dim3(NBLK), dim3(512), 0, stream>>>(hbuf, genes, wt, bt, out);
}

// Round 12
// 75.698 us; speedup vs baseline: 1.0199x; 1.0199x over previous
//
#include <hip/hip_runtime.h>
#include <hip/hip_bf16.h>

#define BB 256
#define NLAT 128
#define HH 64
#define CC 64
#define GG 5000
#define NG 5
#define NBLK (GG / NG)      // 1000 decoder blocks = 8 XCDs x 125
#define GSTRIDE (GG * CC)   // 320000 floats between batch rows
#define BN_EPS 1e-5f

typedef __bf16 bf16x8 __attribute__((ext_vector_type(8)));
typedef float f32x4 __attribute__((ext_vector_type(4)));

// Kernel 1: h = BN(ReLU(latent @ W1 + b1)) -> bf16 [256][64]
__global__ void hprep_kernel(const float* __restrict__ latent,
                             const float* __restrict__ W1,
                             const float* __restrict__ b1,
                             const float* __restrict__ gamma,
                             const float* __restrict__ beta,
                             const float* __restrict__ mean,
                             const float* __restrict__ var,
                             unsigned short* __restrict__ hout) {
    const int b = blockIdx.x;   // 0..255
    const int c = threadIdx.x;  // 0..63
    float acc = b1[c];
    const float* lrow = latent + b * NLAT;
#pragma unroll 8
    for (int k = 0; k < NLAT; ++k)
        acc = fmaf(lrow[k], W1[k * HH + c], acc);
    acc = fmaxf(acc, 0.f);  // ReLU first
    float s = gamma[c] * rsqrtf(var[c] + BN_EPS);
    acc = (acc - mean[c]) * s + beta[c];
    __bf16 hv = (__bf16)acc;
    hout[b * HH + c] = *reinterpret_cast<unsigned short*>(&hv);
}

// Barrier that only drains LDS ops; global loads/stores stay in flight.
__device__ __forceinline__ void barrier_lds_only() {
    asm volatile("s_waitcnt lgkmcnt(0)" ::: "memory");
    __builtin_amdgcn_s_barrier();
    asm volatile("" ::: "memory");
}

// Kernel 2: out[b,g,c] = sum_h h[b,h] * W[gene,h,c] + bias[gene,c]
// Best-measured configuration (round 10, 76.0 us):
//  - 8 waves / 512 threads; wave w owns b-rows [w*32, w*32+32)
//  - operand-swapped MFMA (E = mfma(Wt_frag, h_frag)) -> lane holds 4
//    consecutive c for one b -> full 256B-contiguous row segments
//  - wave-local 8 KB ldsO transpose staging; flush needs NO cross-wave
//    barrier; ONE lgkm-only barrier per gene (ldsW double-buffer handoff)
//  - NON-TEMPORAL stores: bypass the per-XCD write-back L2, whose
//    eviction-order scramble of the sparse 256B-granule dirty set was
//    row-miss bound (R7: +23%)
//  - regular (L2-cached) in-loop W gather trickled one gene ahead
//    (R8/R9 showed upfront NT read bursts serialize and regress)
//  - NG=5 -> 1000 blocks = 2 nearly-full residency generations; exact
//    8x125 chunked bijective XCD swizzle
//  - LDS = 2x8 KB ldsW + 64 KB ldsO = 80 KB -> 2 blocks/CU (the R8
//    regression was +512B pushing this to 1 block/CU)
__global__ __launch_bounds__(512, 4) void decoder_kernel(
    const unsigned short* __restrict__ hbuf,  // bf16 [256][64]
    const int* __restrict__ genes,            // [5000]
    const float* __restrict__ wt,             // [30000][64][64] f32
    const float* __restrict__ bt,             // [30000][64] f32
    float* __restrict__ out)                  // [256][5000][64] f32
{
    __shared__ __align__(16) unsigned short ldsW[2][4096];  // 2 x 8 KB bf16 Wt
    __shared__ __align__(16) float ldsO[BB * CC];           // 64 KB (8 KB/wave)

    const int tid = threadIdx.x;
    const int l   = tid & 63;
    const int w   = tid >> 6;   // wave 0..7
    const int l16 = l & 15;
    const int lg  = l >> 4;     // 0..3

    // Exact chunked XCD swizzle: 1000 blocks = 8 XCDs x 125 consecutive.
    const int xcd = blockIdx.x & 7;
    const int k   = blockIdx.x >> 3;
    const int v   = xcd * 125 + k;
    const int g0  = v * NG;

    // A fragments (persist): rows w*32 + m*16 + l16, k-contiguous 8 bf16
    bf16x8 afrag[2][2];
#pragma unroll
    for (int m = 0; m < 2; ++m)
#pragma unroll
        for (int ks = 0; ks < 2; ++ks) {
            int row = w * 32 + m * 16 + l16;
            afrag[m][ks] = *reinterpret_cast<const bf16x8*>(
                hbuf + row * HH + ks * 32 + lg * 8);
        }

    // W staging geometry: thread stages column sc of h-block shb.
    const int sc  = l;   // 0..63
    const int shb = w;   // 0..7
    const int swz16 = sc * 8 + (shb ^ (sc & 7));

    float pkv[8];

    // --- prologue: stage gene g0 into ldsW[0] (regular cached loads)
    {
        const float* Wg = wt + (size_t)genes[g0] * (HH * CC);
#pragma unroll
        for (int j = 0; j < 8; ++j)
            pkv[j] = Wg[(shb * 8 + j) * CC + sc];
        bf16x8 pk;
#pragma unroll
        for (int j = 0; j < 8; ++j) pk[j] = (__bf16)pkv[j];
        *reinterpret_cast<bf16x8*>(
            reinterpret_cast<char*>(ldsW[0]) + swz16 * 16) = pk;
    }
    barrier_lds_only();

    // wave-local ldsO region: 32 rows x 64 floats = 8 KB
    float* ldsOw = ldsO + w * (32 * CC);

    int p = 0;
#pragma unroll
    for (int i = 0; i < NG; ++i) {
        const int g = g0 + i;

        // 1. issue next gene's gather loads early (hide under MFMA + flush)
        if (i + 1 < NG) {
            const float* Wn = wt + (size_t)genes[g + 1] * (HH * CC);
#pragma unroll
            for (int j = 0; j < 8; ++j)
                pkv[j] = Wn[(shb * 8 + j) * CC + sc];
        }

        // 2. MFMA (operand-swapped): E[n][m] lane = (c = n*16+lg*4+r, b=l16)
        const float* bg = bt + (size_t)genes[g] * CC;
        const char* buf = reinterpret_cast<const char*>(ldsW[p]);
        f32x4 E[4][2];
#pragma unroll
        for (int n = 0; n < 4; ++n) {
            const int c = n * 16 + l16;
            bf16x8 bfr0 = *reinterpret_cast<const bf16x8*>(
                buf + (c * 8 + ((0 + lg) ^ (c & 7))) * 16);
            bf16x8 bfr1 = *reinterpret_cast<const bf16x8*>(
                buf + (c * 8 + ((4 + lg) ^ (c & 7))) * 16);
            f32x4 binit = *reinterpret_cast<const f32x4*>(bg + n * 16 + lg * 4);
#pragma unroll
            for (int m = 0; m < 2; ++m) {
                f32x4 e = binit;
                e = __builtin_amdgcn_mfma_f32_16x16x32_bf16(bfr0, afrag[m][0], e, 0, 0, 0);
                e = __builtin_amdgcn_mfma_f32_16x16x32_bf16(bfr1, afrag[m][1], e, 0, 0, 0);
                E[n][m] = e;
            }
        }

        // 3. E -> wave-local ldsO (rows r = m*16+l16; XOR-swizzled, <=2-way)
#pragma unroll
        for (int n = 0; n < 4; ++n)
#pragma unroll
            for (int m = 0; m < 2; ++m) {
                int r = m * 16 + l16;
                int unit = r * 16 + ((n * 4 + lg) ^ l16);
                *reinterpret_cast<f32x4*>(ldsOw + unit * 4) = E[n][m];
            }

        // 4. flush own rows, NON-TEMPORAL (no cross-wave barrier):
        //    each quarter-wave = one full 256B (b,g) row, conflict-free read
        {
            float* og = out + (size_t)g * CC;
#pragma unroll
            for (int it = 0; it < 8; ++it) {
                int r = it * 4 + lg;              // row within wave region
                int b = w * 32 + r;               // global batch row
                int unit = r * 16 + (l16 ^ (r & 15));
                f32x4 vv = *reinterpret_cast<const f32x4*>(ldsOw + unit * 4);
                __builtin_nontemporal_store(
                    vv, reinterpret_cast<f32x4*>(og + (size_t)b * GSTRIDE + l16 * 4));
            }
        }

        // 5. cvt + ds_write next gene's Wt into buf p^1; ONE barrier/gene
        if (i + 1 < NG) {
            bf16x8 pk;
#pragma unroll
            for (int j = 0; j < 8; ++j) pk[j] = (__bf16)pkv[j];
            *reinterpret_cast<bf16x8*>(
                reinterpret_cast<char*>(ldsW[p ^ 1]) + swz16 * 16) = pk;
            barrier_lds_only();  // all waves' reads of buf p done; p^1 visible
            p ^= 1;
        }
    }
}

extern "C" void kernel_launch(void* const* d_in, const int* in_sizes, int n_in,
                              void* d_out, int out_size, void* d_ws, size_t ws_size,
                              hipStream_t stream) {
    const float* latent = (const float*)d_in[0];
    const int*   genes  = (const int*)d_in[1];
    const float* W1     = (const float*)d_in[2];
    const float* b1     = (const float*)d_in[3];
    const float* gamma  = (const float*)d_in[4];
    const float* beta   = (const float*)d_in[5];
    const float* mean   = (const float*)d_in[6];
    const float* var    = (const float*)d_in[7];
    const float* wt     = (const float*)d_in[8];
    const float* bt     = (const float*)d_in[9];
    float* out = (float*)d_out;
    unsigned short* hbuf = (unsigned short*)d_ws;  // 32 KB bf16 h

    hprep_kernel<<<dim3(BB), dim3(HH), 0, stream>>>(latent, W1, b1, gamma, beta,
                                                    mean, var, hbuf);
    decoder_kernel<<<dim3(NBLK), dim3(512), 0, stream>>>(hbuf, genes, wt, bt, out);
}